// Round 7
// baseline (226.931 us; speedup 1.0000x reference)
//
#include <hip/hip_runtime.h>
#include <hip/hip_bf16.h>

// SimCSE loss: loss = mean_i( logsumexp_j(sim[i][j]) - sim[i][i] ),
// sim = normalize(q) @ normalize(c)^T / 0.05.  N=8192, D=768, fp32 in, scalar out.
//
// GEMM: 256x256 tile, 8 waves (2Mx4N), BK=64, 128KiB LDS dbuf, round-5
// one-barrier-per-phase schedule. Round-7: MFMA 32x32x16 (2495 TF ubench vs
// 2075 for 16x16x32) — same LDS traffic, -17% matrix-pipe window.
// A/B frag: row(col)=lane&31, k=(lane>>5)*8. C/D (HW-verified m74/m101):
// col=lane&31, row=(reg&3)+8*(reg>>2)+4*(lane>>5).

#define NROWS 8192
#define DDIM  768
#define ROWB  1536              // bytes per bf16 row
#define NKT  (DDIM / 64)        // 12 K-tiles
#define NIT  (NKT / 2)          // 6 iterations
#define GRID_T (NROWS / 256)    // 32 tiles per dim

constexpr float INV_TEMP = 20.0f;   // 1/0.05
constexpr float NORM_EPS = 1e-8f;

using bf16 = __hip_bfloat16;
typedef __attribute__((ext_vector_type(16))) float f32x16;
typedef __attribute__((ext_vector_type(8)))  short bf16x8;

// ---------------------------------------------------------------- fused normalize + diag
__global__ void norm_diag_kernel(const float* __restrict__ q, const float* __restrict__ c,
                                 bf16* __restrict__ qn, bf16* __restrict__ cn,
                                 float* __restrict__ diag) {
    const int row  = (blockIdx.x * 256 + threadIdx.x) >> 6;
    const int lane = threadIdx.x & 63;
    const float4* qv = (const float4*)(q + (size_t)row * DDIM);
    const float4* cv = (const float4*)(c + (size_t)row * DDIM);
    float4 a[3], b[3];
    #pragma unroll
    for (int j = 0; j < 3; ++j) { a[j] = qv[lane + j * 64]; b[j] = cv[lane + j * 64]; }
    float ssq = 0.f, ssc = 0.f, dot = 0.f;
    #pragma unroll
    for (int j = 0; j < 3; ++j) {
        ssq += a[j].x * a[j].x + a[j].y * a[j].y + a[j].z * a[j].z + a[j].w * a[j].w;
        ssc += b[j].x * b[j].x + b[j].y * b[j].y + b[j].z * b[j].z + b[j].w * b[j].w;
        dot += a[j].x * b[j].x + a[j].y * b[j].y + a[j].z * b[j].z + a[j].w * b[j].w;
    }
    #pragma unroll
    for (int m = 32; m; m >>= 1) {
        ssq += __shfl_xor(ssq, m);
        ssc += __shfl_xor(ssc, m);
        dot += __shfl_xor(dot, m);
    }
    float invq = 1.0f / fmaxf(sqrtf(ssq), NORM_EPS);
    float invc = 1.0f / fmaxf(sqrtf(ssc), NORM_EPS);
    if (lane == 0) diag[row] = dot * invq * invc * INV_TEMP;
    ushort4* qo = (ushort4*)(qn + (size_t)row * DDIM);
    ushort4* co = (ushort4*)(cn + (size_t)row * DDIM);
    #pragma unroll
    for (int j = 0; j < 3; ++j) {
        union { ushort4 u; bf16 h[4]; } oq, oc;
        oq.h[0] = __float2bfloat16(a[j].x * invq); oq.h[1] = __float2bfloat16(a[j].y * invq);
        oq.h[2] = __float2bfloat16(a[j].z * invq); oq.h[3] = __float2bfloat16(a[j].w * invq);
        oc.h[0] = __float2bfloat16(b[j].x * invc); oc.h[1] = __float2bfloat16(b[j].y * invc);
        oc.h[2] = __float2bfloat16(b[j].z * invc); oc.h[3] = __float2bfloat16(b[j].w * invc);
        qo[lane + j * 64] = oq.u;
        co[lane + j * 64] = oc.u;
    }
}

// ---------------------------------------------------------------- GEMM + expsum
__device__ __forceinline__ void async16(void* l, const void* g) {
    __builtin_amdgcn_global_load_lds(
        (const __attribute__((address_space(1))) void*)g,
        (__attribute__((address_space(3))) void*)l, 16, 0, 0);
}

#define BARRIER __builtin_amdgcn_s_barrier()
#define SCHED0  __builtin_amdgcn_sched_barrier(0)
#define PRIO1   __builtin_amdgcn_s_setprio(1)
#define PRIO0   __builtin_amdgcn_s_setprio(0)
#define VMCNT(n) do { asm volatile("s_waitcnt vmcnt(" #n ")" ::: "memory"); } while (0)

// LDS map (bytes): parity p: A at p*65536, B at 32768 + p*65536; half h at +h*16384.
#define STAGE_A(P, H, KT) do {                                              \
    const char* _g = aG + (size_t)(H) * 128 * ROWB + (size_t)(KT) * 128;    \
    char* _l = lds + (P) * 65536 + (H) * 16384 + dstW;                      \
    async16(_l, _g);                                                        \
    async16(_l + 8192, _g + 64 * ROWB);                                     \
} while (0)
#define STAGE_B(P, H, KT) do {                                              \
    const char* _g = bG + (size_t)(H) * 128 * ROWB + (size_t)(KT) * 128;    \
    char* _l = lds + 32768 + (P) * 65536 + (H) * 16384 + dstW;              \
    async16(_l, _g);                                                        \
    async16(_l + 8192, _g + 64 * ROWB);                                     \
} while (0)

// 8 x ds_read_b128: A frags for row-half MH (rows wr*128 + MH*64 + mi*32 + (lane&31))
#define READ_A(P, MH) do {                                                  \
    const char* _ab = lds + (P) * 65536 + aBaseT + (MH) * 8192;             \
    _Pragma("unroll") for (int mi = 0; mi < 2; ++mi)                        \
    _Pragma("unroll") for (int ks = 0; ks < 4; ++ks)                        \
        a[mi][ks] = *(const bf16x8*)(_ab + mi * 4096 + xkk[ks]);            \
} while (0)
// 4 x ds_read_b128: B frag for col-half NH (cols wc*64 + NH*32 + (lane&31))
#define READ_B(P, NH) do {                                                  \
    const char* _bb = lds + 32768 + (P) * 65536 + bBaseT + (NH) * 4096;     \
    _Pragma("unroll") for (int ks = 0; ks < 4; ++ks)                        \
        bfr[NH][ks] = *(const bf16x8*)(_bb + xkk[ks]);                      \
} while (0)

// 8 MFMA 32x32x16: quadrant (MH, NH), K=64 (4 k-steps), accumulate in place
#define MFMA_Q(MH, NH)                                                      \
    _Pragma("unroll") for (int mi = 0; mi < 2; ++mi)                        \
    _Pragma("unroll") for (int ks = 0; ks < 4; ++ks)                        \
        acc[(MH)*2+mi][NH] = __builtin_amdgcn_mfma_f32_32x32x16_bf16(       \
            a[mi][ks], bfr[NH][ks], acc[(MH)*2+mi][NH], 0, 0, 0);

__launch_bounds__(512, 2)
__global__ void simgemm_kernel(const bf16* __restrict__ A, const bf16* __restrict__ B,
                               float* __restrict__ partial) {
    __shared__ __attribute__((aligned(16))) char smem[131072];
    char* lds = smem;

    const int bid = blockIdx.x;
    const int tm = bid >> 5, tn = bid & 31;
    const int rowBase = tm * 256, colBase = tn * 256;
    const int tid = threadIdx.x;
    const int wid = tid >> 6, lane = tid & 63;
    const int wr = wid >> 2, wc = wid & 3;

    // staging source (pre-swizzled involution; read side applies same XOR)
    const int sr  = tid >> 3;
    const int scb = ((tid & 7) * 16) ^ ((sr & 7) << 4);
    const char* aG = (const char*)A + (size_t)(rowBase + sr) * ROWB + scb;
    const char* bG = (const char*)B + (size_t)(colBase + sr) * ROWB + scb;
    const int dstW = wid * 1024;

    // ds_read addressing (32x32 frags): row = lane&31, k-lane = (lane>>5)*8 elems
    const int aBaseT = wr * 16384 + (lane & 31) * 128;
    const int bBaseT = (wc >> 1) * 16384 + (wc & 1) * 8192 + (lane & 31) * 128;
    const int kl2  = (lane >> 5) * 16;           // bytes
    const int swzr = (lane & 7) << 4;
    int xkk[4];
    #pragma unroll
    for (int ks = 0; ks < 4; ++ks) xkk[ks] = (ks * 32 + kl2) ^ swzr;

    f32x16 acc[4][2] = {};
    bf16x8 a[2][4];
    bf16x8 bfr[2][4];

    // ---- prologue: stage tile0 (buf0) fully + tile1 A halves (buf1)
    STAGE_A(0, 0, 0); STAGE_A(0, 1, 0);
    STAGE_B(0, 0, 0); STAGE_B(0, 1, 0);
    STAGE_A(1, 0, 1); STAGE_A(1, 1, 1);
    VMCNT(4);          // tile0 landed; tile1.A (4 loads) in flight
    BARRIER; SCHED0;
    READ_B(0, 0); READ_A(0, 0);
    SCHED0;

    #pragma unroll 1
    for (int i = 0; i < NIT; ++i) {
        const int t1 = 2 * i + 1;
        const int t2 = 2 * i + 2, t3 = 2 * i + 3;
        const bool more = (i + 1 < NIT);
        // ph1: MFMA even(0,0); stage tO.B0 | after bar: read tE.B1
        STAGE_B(1, 0, t1);
        PRIO1; MFMA_Q(0, 0); PRIO0;
        VMCNT(6);
        BARRIER; SCHED0;
        READ_B(0, 1); SCHED0;
        // ph2: MFMA(0,1); stage tO.B1 | read tE.A1
        STAGE_B(1, 1, t1);
        PRIO1; MFMA_Q(0, 1); PRIO0;
        BARRIER; SCHED0;
        READ_A(0, 1); SCHED0;
        // ph3: MFMA(1,0); stage t2.A0
        if (more) STAGE_A(0, 0, t2);
        PRIO1; MFMA_Q(1, 0); PRIO0;
        BARRIER; SCHED0;
        // ph4: MFMA(1,1); stage t2.A1 | read tO.B0, tO.A0
        if (more) STAGE_A(0, 1, t2);
        PRIO1; MFMA_Q(1, 1); PRIO0;
        if (more) { VMCNT(6); } else { VMCNT(0); }
        BARRIER; SCHED0;
        READ_B(1, 0); READ_A(1, 0); SCHED0;
        // ph5: MFMA odd(0,0); stage t2.B0 | read tO.B1
        if (more) STAGE_B(0, 0, t2);
        PRIO1; MFMA_Q(0, 0); PRIO0;
        if (more) { VMCNT(6); }
        BARRIER; SCHED0;
        READ_B(1, 1); SCHED0;
        // ph6: MFMA(0,1); stage t2.B1 | read tO.A1
        if (more) STAGE_B(0, 1, t2);
        PRIO1; MFMA_Q(0, 1); PRIO0;
        BARRIER; SCHED0;
        READ_A(1, 1); SCHED0;
        // ph7: MFMA(1,0); stage t3.A0
        if (more) STAGE_A(1, 0, t3);
        PRIO1; MFMA_Q(1, 0); PRIO0;
        BARRIER; SCHED0;
        // ph8: MFMA(1,1); stage t3.A1 | read t2.B0, t2.A0
        if (more) STAGE_A(1, 1, t3);
        PRIO1; MFMA_Q(1, 1); PRIO0;
        if (more) { VMCNT(6); }
        BARRIER; SCHED0;
        if (more) { READ_B(0, 0); READ_A(0, 0); SCHED0; }
    }

    // ---- epilogue: rowsum of exp(20*acc - 20) over this tile's 256 cols
    // C/D: col = lane&31, row = F*32 + (r&3) + 8*(r>>2) + 4*(lane>>5)
    __syncthreads();                       // all loads drained (VMCNT(0) in last ph4)
    float* red = (float*)smem;             // [256][4]
    #pragma unroll
    for (int F = 0; F < 4; ++F) {
        #pragma unroll
        for (int r = 0; r < 16; ++r) {
            float s = __expf(fmaf(INV_TEMP, acc[F][0][r], -INV_TEMP))
                    + __expf(fmaf(INV_TEMP, acc[F][1][r], -INV_TEMP));
            s += __shfl_xor(s, 1);
            s += __shfl_xor(s, 2);
            s += __shfl_xor(s, 4);
            s += __shfl_xor(s, 8);
            s += __shfl_xor(s, 16);
            if ((lane & 31) == 0)
                red[(wr * 128 + F * 32 + (r & 3) + 8 * (r >> 2) + 4 * (lane >> 5)) * 4 + wc] = s;
        }
    }
    __syncthreads();
    if (tid < 256)
        partial[(size_t)(rowBase + tid) * GRID_T + tn] =
            red[tid * 4 + 0] + red[tid * 4 + 1] + red[tid * 4 + 2] + red[tid * 4 + 3];
}

// ---------------------------------------------------------------- finalize
__global__ void finalize_kernel(const float* __restrict__ partial,
                                const float* __restrict__ diag,
                                float* __restrict__ out) {
    int row = blockIdx.x * 256 + threadIdx.x;
    const float4* p = (const float4*)(partial + (size_t)row * GRID_T);
    float z = 0.f;
    #pragma unroll
    for (int i = 0; i < GRID_T / 4; ++i) {
        float4 v = p[i];
        z += v.x + v.y + v.z + v.w;
    }
    float term = INV_TEMP + logf(z) - diag[row];
    #pragma unroll
    for (int m = 32; m; m >>= 1) term += __shfl_xor(term, m);
    __shared__ float wsum[4];
    if ((threadIdx.x & 63) == 0) wsum[threadIdx.x >> 6] = term;
    __syncthreads();
    if (threadIdx.x == 0) {
        float s = wsum[0] + wsum[1] + wsum[2] + wsum[3];
        atomicAdd(out, s * (1.0f / NROWS));
    }
}

// ---------------------------------------------------------------- launch
extern "C" void kernel_launch(void* const* d_in, const int* in_sizes, int n_in,
                              void* d_out, int out_size, void* d_ws, size_t ws_size,
                              hipStream_t stream) {
    const float* q = (const float*)d_in[0];
    const float* c = (const float*)d_in[1];
    float* out = (float*)d_out;

    char* ws = (char*)d_ws;
    bf16* qn = (bf16*)ws;                                        // 12.6 MB
    bf16* cn = (bf16*)(ws + (size_t)NROWS * DDIM * 2);           // 12.6 MB
    float* diag = (float*)(ws + (size_t)NROWS * DDIM * 4);       // 32 KB
    float* partial = diag + NROWS;                               // 1 MB

    hipMemsetAsync(d_out, 0, sizeof(float), stream);

    norm_diag_kernel<<<NROWS / 4, 256, 0, stream>>>(q, c, qn, cn, diag);
    simgemm_kernel<<<GRID_T * GRID_T, 512, 0, stream>>>(qn, cn, partial);
    finalize_kernel<<<NROWS / 256, 256, 0, stream>>>(partial, diag, out);
}

// Round 8
// 192.229 us; speedup vs baseline: 1.1805x; 1.1805x over previous
//
#include <hip/hip_runtime.h>
#include <hip/hip_bf16.h>

// SimCSE loss: loss = mean_i( logsumexp_j(sim[i][j]) - sim[i][i] ),
// sim = normalize(q) @ normalize(c)^T / 0.05.  N=8192, D=768, fp32 in, scalar out.
//
// GEMM: 256x256 tile, 8 waves (2Mx4N), 16x16x32 MFMA, BK=64, 128KiB LDS dbuf.
// Round-8: round-5 one-barrier pipeline merged to 4 phases/iter (2 barriers +
// 1 vmcnt per K-tile). Each phase: {stage 4 loads; 32 MFMA; [vmcnt]; barrier;
// pipelined reads for next phase}. Reads ordered B-then-A so partial lgkm
// waits let the first MFMAs start early. 32x32 MFMA rejected (round 7):
// 32-row frags -> 4-way LDS conflicts with the 8-row XOR swizzle.

#define NROWS 8192
#define DDIM  768
#define ROWB  1536              // bytes per bf16 row
#define NKT  (DDIM / 64)        // 12 K-tiles
#define NIT  (NKT / 2)          // 6 iterations
#define GRID_T (NROWS / 256)    // 32 tiles per dim

constexpr float INV_TEMP = 20.0f;   // 1/0.05
constexpr float NORM_EPS = 1e-8f;

using bf16 = __hip_bfloat16;
typedef __attribute__((ext_vector_type(4))) float  f32x4;
typedef __attribute__((ext_vector_type(8))) short  bf16x8;

// ---------------------------------------------------------------- fused normalize + diag
__global__ void norm_diag_kernel(const float* __restrict__ q, const float* __restrict__ c,
                                 bf16* __restrict__ qn, bf16* __restrict__ cn,
                                 float* __restrict__ diag) {
    const int row  = (blockIdx.x * 256 + threadIdx.x) >> 6;
    const int lane = threadIdx.x & 63;
    const float4* qv = (const float4*)(q + (size_t)row * DDIM);
    const float4* cv = (const float4*)(c + (size_t)row * DDIM);
    float4 a[3], b[3];
    #pragma unroll
    for (int j = 0; j < 3; ++j) { a[j] = qv[lane + j * 64]; b[j] = cv[lane + j * 64]; }
    float ssq = 0.f, ssc = 0.f, dot = 0.f;
    #pragma unroll
    for (int j = 0; j < 3; ++j) {
        ssq += a[j].x * a[j].x + a[j].y * a[j].y + a[j].z * a[j].z + a[j].w * a[j].w;
        ssc += b[j].x * b[j].x + b[j].y * b[j].y + b[j].z * b[j].z + b[j].w * b[j].w;
        dot += a[j].x * b[j].x + a[j].y * b[j].y + a[j].z * b[j].z + a[j].w * b[j].w;
    }
    #pragma unroll
    for (int m = 32; m; m >>= 1) {
        ssq += __shfl_xor(ssq, m);
        ssc += __shfl_xor(ssc, m);
        dot += __shfl_xor(dot, m);
    }
    float invq = 1.0f / fmaxf(sqrtf(ssq), NORM_EPS);
    float invc = 1.0f / fmaxf(sqrtf(ssc), NORM_EPS);
    if (lane == 0) diag[row] = dot * invq * invc * INV_TEMP;
    ushort4* qo = (ushort4*)(qn + (size_t)row * DDIM);
    ushort4* co = (ushort4*)(cn + (size_t)row * DDIM);
    #pragma unroll
    for (int j = 0; j < 3; ++j) {
        union { ushort4 u; bf16 h[4]; } oq, oc;
        oq.h[0] = __float2bfloat16(a[j].x * invq); oq.h[1] = __float2bfloat16(a[j].y * invq);
        oq.h[2] = __float2bfloat16(a[j].z * invq); oq.h[3] = __float2bfloat16(a[j].w * invq);
        oc.h[0] = __float2bfloat16(b[j].x * invc); oc.h[1] = __float2bfloat16(b[j].y * invc);
        oc.h[2] = __float2bfloat16(b[j].z * invc); oc.h[3] = __float2bfloat16(b[j].w * invc);
        qo[lane + j * 64] = oq.u;
        co[lane + j * 64] = oc.u;
    }
}

// ---------------------------------------------------------------- GEMM + expsum
__device__ __forceinline__ void async16(void* l, const void* g) {
    __builtin_amdgcn_global_load_lds(
        (const __attribute__((address_space(1))) void*)g,
        (__attribute__((address_space(3))) void*)l, 16, 0, 0);
}

#define BARRIER __builtin_amdgcn_s_barrier()
#define SCHED0  __builtin_amdgcn_sched_barrier(0)
#define PRIO1   __builtin_amdgcn_s_setprio(1)
#define PRIO0   __builtin_amdgcn_s_setprio(0)
#define VMCNT(n) do { asm volatile("s_waitcnt vmcnt(" #n ")" ::: "memory"); } while (0)

// LDS map (bytes): parity p: A at p*65536, B at 32768 + p*65536; half h at +h*16384.
#define STAGE_A(P, H, KT) do {                                              \
    const char* _g = aG + (size_t)(H) * 128 * ROWB + (size_t)(KT) * 128;    \
    char* _l = lds + (P) * 65536 + (H) * 16384 + dstW;                      \
    async16(_l, _g);                                                        \
    async16(_l + 8192, _g + 64 * ROWB);                                     \
} while (0)
#define STAGE_B(P, H, KT) do {                                              \
    const char* _g = bG + (size_t)(H) * 128 * ROWB + (size_t)(KT) * 128;    \
    char* _l = lds + 32768 + (P) * 65536 + (H) * 16384 + dstW;              \
    async16(_l, _g);                                                        \
    async16(_l + 8192, _g + 64 * ROWB);                                     \
} while (0)

#define READ_A(P, MH) do {                                                  \
    const char* _ab = lds + (P) * 65536 + aBaseT + (MH) * 64 * 128;         \
    _Pragma("unroll") for (int mi = 0; mi < 4; ++mi) {                      \
        a[mi][0] = *(const bf16x8*)(_ab + mi * 2048 + xk0);                 \
        a[mi][1] = *(const bf16x8*)(_ab + mi * 2048 + xk1);                 \
    }                                                                       \
} while (0)
#define READ_B(P, NH) do {                                                  \
    const char* _bb = lds + 32768 + (P) * 65536 + bBaseT + (NH) * 32 * 128; \
    _Pragma("unroll") for (int ni = 0; ni < 2; ++ni) {                      \
        bfr[NH][ni][0] = *(const bf16x8*)(_bb + ni * 2048 + xk0);           \
        bfr[NH][ni][1] = *(const bf16x8*)(_bb + ni * 2048 + xk1);           \
    }                                                                       \
} while (0)

#define MFMA_Q(MH, NH)                                                      \
    _Pragma("unroll") for (int mi = 0; mi < 4; ++mi)                        \
    _Pragma("unroll") for (int ni = 0; ni < 2; ++ni) {                      \
        acc[(MH)*4+mi][(NH)*2+ni] = __builtin_amdgcn_mfma_f32_16x16x32_bf16(\
            a[mi][0], bfr[NH][ni][0], acc[(MH)*4+mi][(NH)*2+ni], 0, 0, 0);  \
        acc[(MH)*4+mi][(NH)*2+ni] = __builtin_amdgcn_mfma_f32_16x16x32_bf16(\
            a[mi][1], bfr[NH][ni][1], acc[(MH)*4+mi][(NH)*2+ni], 0, 0, 0);  \
    }

__launch_bounds__(512, 2)
__global__ void simgemm_kernel(const bf16* __restrict__ A, const bf16* __restrict__ B,
                               float* __restrict__ partial) {
    __shared__ __attribute__((aligned(16))) char smem[131072];
    char* lds = smem;

    const int bid = blockIdx.x;
    const int tm = bid >> 5, tn = bid & 31;
    const int rowBase = tm * 256, colBase = tn * 256;
    const int tid = threadIdx.x;
    const int wid = tid >> 6, lane = tid & 63;
    const int wr = wid >> 2, wc = wid & 3;

    // staging source (pre-swizzled involution; read side applies same XOR)
    const int sr  = tid >> 3;
    const int scb = ((tid & 7) * 16) ^ ((sr & 7) << 4);
    const char* aG = (const char*)A + (size_t)(rowBase + sr) * ROWB + scb;
    const char* bG = (const char*)B + (size_t)(colBase + sr) * ROWB + scb;
    const int dstW = wid * 1024;

    const int aBaseT = wr * 16384 + (lane & 15) * 128;
    const int bBaseT = (wc >> 1) * 16384 + ((wc & 1) * 64 + (lane & 15)) * 128;
    const int klane  = (lane >> 4) * 16;
    const int swzr   = (lane & 7) << 4;
    const int xk0    = klane ^ swzr;
    const int xk1    = (64 + klane) ^ swzr;

    f32x4  acc[8][4] = {};
    bf16x8 a[4][2];
    bf16x8 bfr[2][2][2];

    // ---- prologue: stage tile0 (buf0) fully + tile1 A halves (buf1)
    STAGE_A(0, 0, 0); STAGE_A(0, 1, 0);
    STAGE_B(0, 0, 0); STAGE_B(0, 1, 0);
    STAGE_A(1, 0, 1); STAGE_A(1, 1, 1);
    VMCNT(4);          // tile0 landed; tile1.A (4 loads) in flight
    BARRIER; SCHED0;
    READ_B(0, 0); READ_A(0, 0);
    SCHED0;

    #pragma unroll 1
    for (int i = 0; i < NIT; ++i) {
        const int t1 = 2 * i + 1;
        const int t2 = 2 * i + 2, t3 = 2 * i + 3;
        const bool more = (i + 1 < NIT);
        // MP1: MFMA even (0,0)+(0,1); stage t1.B; read tE.B1 just-in-time
        STAGE_B(1, 0, t1); STAGE_B(1, 1, t1);
        READ_B(0, 1); SCHED0;
        PRIO1; MFMA_Q(0, 0); MFMA_Q(0, 1); PRIO0;
        BARRIER; SCHED0;
        READ_A(0, 1); SCHED0;
        // MP2: MFMA even (1,0)+(1,1); stage t2.A; vmcnt -> t1 landed
        if (more) { STAGE_A(0, 0, t2); STAGE_A(0, 1, t2); }
        PRIO1; MFMA_Q(1, 0); MFMA_Q(1, 1); PRIO0;
        if (more) { VMCNT(4); } else { VMCNT(0); }
        BARRIER; SCHED0;
        READ_B(1, 0); READ_A(1, 0); SCHED0;
        // MP3: MFMA odd (0,0)+(0,1); stage t2.B; read tO.B1 just-in-time
        if (more) { STAGE_B(0, 0, t2); STAGE_B(0, 1, t2); }
        READ_B(1, 1); SCHED0;
        PRIO1; MFMA_Q(0, 0); MFMA_Q(0, 1); PRIO0;
        BARRIER; SCHED0;
        READ_A(1, 1); SCHED0;
        // MP4: MFMA odd (1,0)+(1,1); stage t3.A; vmcnt -> t2 landed
        if (more) { STAGE_A(1, 0, t3); STAGE_A(1, 1, t3); }
        PRIO1; MFMA_Q(1, 0); MFMA_Q(1, 1); PRIO0;
        if (more) { VMCNT(4); }
        BARRIER; SCHED0;
        if (more) { READ_B(0, 0); READ_A(0, 0); SCHED0; }
    }

    // ---- epilogue: rowsum of exp(20*acc - 20) over this tile's 256 cols
    // C/D layout (16x16x32): col = lane&15, row = (lane>>4)*4 + r
    __syncthreads();                       // all loads drained (VMCNT(0) in last MP2)
    float* red = (float*)smem;             // [256][4]
    #pragma unroll
    for (int m = 0; m < 8; ++m) {
        #pragma unroll
        for (int r = 0; r < 4; ++r) {
            float s = 0.f;
            #pragma unroll
            for (int n = 0; n < 4; ++n)
                s += __expf(fmaf(INV_TEMP, acc[m][n][r], -INV_TEMP));
            s += __shfl_xor(s, 1);
            s += __shfl_xor(s, 2);
            s += __shfl_xor(s, 4);
            s += __shfl_xor(s, 8);
            if ((lane & 15) == 0)
                red[(wr * 128 + m * 16 + (lane >> 4) * 4 + r) * 4 + wc] = s;
        }
    }
    __syncthreads();
    if (tid < 256)
        partial[(size_t)(rowBase + tid) * GRID_T + tn] =
            red[tid * 4 + 0] + red[tid * 4 + 1] + red[tid * 4 + 2] + red[tid * 4 + 3];
}

// ---------------------------------------------------------------- finalize
__global__ void finalize_kernel(const float* __restrict__ partial,
                                const float* __restrict__ diag,
                                float* __restrict__ out) {
    int row = blockIdx.x * 256 + threadIdx.x;
    const float4* p = (const float4*)(partial + (size_t)row * GRID_T);
    float z = 0.f;
    #pragma unroll
    for (int i = 0; i < GRID_T / 4; ++i) {
        float4 v = p[i];
        z += v.x + v.y + v.z + v.w;
    }
    float term = INV_TEMP + logf(z) - diag[row];
    #pragma unroll
    for (int m = 32; m; m >>= 1) term += __shfl_xor(term, m);
    __shared__ float wsum[4];
    if ((threadIdx.x & 63) == 0) wsum[threadIdx.x >> 6] = term;
    __syncthreads();
    if (threadIdx.x == 0) {
        float s = wsum[0] + wsum[1] + wsum[2] + wsum[3];
        atomicAdd(out, s * (1.0f / NROWS));
    }
}

// ---------------------------------------------------------------- launch
extern "C" void kernel_launch(void* const* d_in, const int* in_sizes, int n_in,
                              void* d_out, int out_size, void* d_ws, size_t ws_size,
                              hipStream_t stream) {
    const float* q = (const float*)d_in[0];
    const float* c = (const float*)d_in[1];
    float* out = (float*)d_out;

    char* ws = (char*)d_ws;
    bf16* qn = (bf16*)ws;                                        // 12.6 MB
    bf16* cn = (bf16*)(ws + (size_t)NROWS * DDIM * 2);           // 12.6 MB
    float* diag = (float*)(ws + (size_t)NROWS * DDIM * 4);       // 32 KB
    float* partial = diag + NROWS;                               // 1 MB

    hipMemsetAsync(d_out, 0, sizeof(float), stream);

    norm_diag_kernel<<<NROWS / 4, 256, 0, stream>>>(q, c, qn, cn, diag);
    simgemm_kernel<<<GRID_T * GRID_T, 512, 0, stream>>>(qn, cn, partial);
    finalize_kernel<<<NROWS / 256, 256, 0, stream>>>(partial, diag, out);
}